// Round 3
// baseline (817.519 us; speedup 1.0000x reference)
//
#include <hip/hip_runtime.h>
#include <hip/hip_bf16.h>
#include <stdint.h>

// GATv2 x2 fused pipeline, fp32 end-to-end.
// N=50000 nodes, E=800000 edges, 128 -> 256 -> 32, mean over nodes -> [32].

#define NN 50000
#define NE 800000
#define DIN 128
#define DE 16
#define HID 256
#define OUTD 32
#define SLOPE 0.2f
#define FILLBLKS 3125

// ---------------- CSR build ----------------

__global__ void k_count(const int* __restrict__ dstv, int* __restrict__ deg) {
  int e = blockIdx.x * 256 + threadIdx.x;
  if (e < NE) atomicAdd(&deg[dstv[e]], 1);
}

__global__ __launch_bounds__(1024) void k_scan(const int* __restrict__ deg,
                                               int* __restrict__ rowptr) {
  __shared__ int lds[1024];
  const int t = threadIdx.x;
  const int CH = 49;  // ceil(50000/1024)
  const int base = t * CH;
  int s = 0;
  for (int i = 0; i < CH; ++i) {
    int idx = base + i;
    if (idx < NN) s += deg[idx];
  }
  lds[t] = s;
  __syncthreads();
  int v = s;
  for (int off = 1; off < 1024; off <<= 1) {
    int add = (t >= off) ? lds[t - off] : 0;
    __syncthreads();
    v += add;
    lds[t] = v;
    __syncthreads();
  }
  int run = v - s;  // exclusive prefix
  for (int i = 0; i < CH; ++i) {
    int idx = base + i;
    if (idx < NN) {
      rowptr[idx] = run;
      run += deg[idx];
    }
  }
  if (t == 1023) rowptr[NN] = run;
}

// fill CSR with (edge_id, src) packed; overlapped with layer-1 node transforms
__global__ __launch_bounds__(256) void k_fill_xform1(
    const int* __restrict__ srcv, const int* __restrict__ dstv,
    const int* __restrict__ rowptr, int* __restrict__ fill, int2* __restrict__ es,
    const float* __restrict__ x, const float* __restrict__ Wl,
    const float* __restrict__ bl, const float* __restrict__ Wr,
    const float* __restrict__ br, float* __restrict__ xl, float* __restrict__ xr) {
  const int bid = blockIdx.x;
  if (bid < FILLBLKS) {
    int e = bid * 256 + threadIdx.x;
    if (e < NE) {
      int d = dstv[e];
      int p = atomicAdd(&fill[d], 1);
      es[rowptr[d] + p] = make_int2(e, srcv[e]);
    }
    return;
  }
  // ---- xform1: 16 rows x 256 cols per block ----
  const int c = threadIdx.x;
  const int r0 = (bid - FILLBLKS) * 16;
  float accl[16], accr[16];
#pragma unroll
  for (int r = 0; r < 16; ++r) { accl[r] = 0.f; accr[r] = 0.f; }
  const float* __restrict__ xb = x + (size_t)r0 * DIN;
#pragma unroll 4
  for (int k = 0; k < DIN; ++k) {
    const float wl = Wl[k * HID + c];
    const float wr = Wr[k * HID + c];
#pragma unroll
    for (int r = 0; r < 16; ++r) {
      const float xv = xb[r * DIN + k];
      accl[r] = fmaf(xv, wl, accl[r]);
      accr[r] = fmaf(xv, wr, accr[r]);
    }
  }
  const float blc = bl[c], brc = br[c];
#pragma unroll
  for (int r = 0; r < 16; ++r) {
    xl[(size_t)(r0 + r) * HID + c] = accl[r] + blc;
    xr[(size_t)(r0 + r) * HID + c] = accr[r] + brc;
  }
}

// ---------------- layer-1 fused edge kernel ----------------
// wave/node, online softmax (exact deferred-rescale), unroll-4,
// self-loop attr accumulated on the fly (sum of per-edge ee / deg).

__global__ __launch_bounds__(256) void k_edge1(
    const float* __restrict__ xl, const float* __restrict__ xr,
    const float* __restrict__ eattr, const int* __restrict__ rowptr,
    const int2* __restrict__ es, const float* __restrict__ We,
    const float* __restrict__ att, const float* __restrict__ bias,
    float* __restrict__ hout) {
  const int tid = threadIdx.x;
  const int lane = tid & 63;
  const int wid = tid >> 6;
  const int node = blockIdx.x * 4 + wid;
  const int c0 = lane << 2;  // 4 channels per lane

  float we[DE][4];
#pragma unroll
  for (int k = 0; k < DE; ++k) {
    const float4 w4 = *(const float4*)(We + k * HID + c0);
    we[k][0] = w4.x; we[k][1] = w4.y; we[k][2] = w4.z; we[k][3] = w4.w;
  }
  const float4 attv = *(const float4*)(att + c0);
  const float4 xrv = *(const float4*)(xr + (size_t)node * HID + c0);
  const int r0 = rowptr[node], r1 = rowptr[node + 1];
  const int deg = r1 - r0;

  float m = -3.0e38f, ssum = 0.f;
  float a0 = 0.f, a1 = 0.f, a2 = 0.f, a3 = 0.f;
  float s0 = 0.f, s1 = 0.f, s2 = 0.f, s3 = 0.f;  // sum of ee over edges

  // ee for one edge from (uniform-address) edge attr
  auto eecalc = [&](const float* __restrict__ ap, float& e0, float& e1, float& e2,
                    float& e3) {
    e0 = e1 = e2 = e3 = 0.f;
#pragma unroll
    for (int k = 0; k < DE; ++k) {
      const float a = ap[k];
      e0 = fmaf(a, we[k][0], e0);
      e1 = fmaf(a, we[k][1], e1);
      e2 = fmaf(a, we[k][2], e2);
      e3 = fmaf(a, we[k][3], e3);
    }
  };
  // leaky-relu (max form) + att dot, per-lane partial
  auto pfin = [&](const float4 xs, float e0, float e1, float e2, float e3) -> float {
    float z0 = xs.x + xrv.x + e0;
    float z1 = xs.y + xrv.y + e1;
    float z2 = xs.z + xrv.z + e2;
    float z3 = xs.w + xrv.w + e3;
    z0 = fmaxf(z0, SLOPE * z0);
    z1 = fmaxf(z1, SLOPE * z1);
    z2 = fmaxf(z2, SLOPE * z2);
    z3 = fmaxf(z3, SLOPE * z3);
    float p = z0 * attv.x;
    p = fmaf(z1, attv.y, p);
    p = fmaf(z2, attv.z, p);
    p = fmaf(z3, attv.w, p);
    return p;
  };
  // exact online-softmax update; p is wave-uniform -> scalar branch
  auto upd = [&](float p, const float4 xs) {
    if (p <= m) {
      const float w = __expf(p - m);
      ssum += w;
      a0 = fmaf(w, xs.x, a0);
      a1 = fmaf(w, xs.y, a1);
      a2 = fmaf(w, xs.z, a2);
      a3 = fmaf(w, xs.w, a3);
    } else {
      const float r = __expf(m - p);
      ssum = fmaf(ssum, r, 1.f);
      a0 = fmaf(a0, r, xs.x);
      a1 = fmaf(a1, r, xs.y);
      a2 = fmaf(a2, r, xs.z);
      a3 = fmaf(a3, r, xs.w);
      m = p;
    }
  };

  int j = r0;
  for (; j + 4 <= r1; j += 4) {
    const int2 q0 = es[j], q1 = es[j + 1], q2 = es[j + 2], q3 = es[j + 3];
    const float4 xs0 = *(const float4*)(xl + (size_t)q0.y * HID + c0);
    const float4 xs1 = *(const float4*)(xl + (size_t)q1.y * HID + c0);
    const float4 xs2 = *(const float4*)(xl + (size_t)q2.y * HID + c0);
    const float4 xs3 = *(const float4*)(xl + (size_t)q3.y * HID + c0);
    float e00, e01, e02, e03, e10, e11, e12, e13;
    float e20, e21, e22, e23, e30, e31, e32, e33;
    eecalc(eattr + (size_t)q0.x * DE, e00, e01, e02, e03);
    eecalc(eattr + (size_t)q1.x * DE, e10, e11, e12, e13);
    eecalc(eattr + (size_t)q2.x * DE, e20, e21, e22, e23);
    eecalc(eattr + (size_t)q3.x * DE, e30, e31, e32, e33);
    s0 += e00 + e10 + e20 + e30;
    s1 += e01 + e11 + e21 + e31;
    s2 += e02 + e12 + e22 + e32;
    s3 += e03 + e13 + e23 + e33;
    float p0 = pfin(xs0, e00, e01, e02, e03);
    float p1 = pfin(xs1, e10, e11, e12, e13);
    float p2 = pfin(xs2, e20, e21, e22, e23);
    float p3 = pfin(xs3, e30, e31, e32, e33);
#pragma unroll
    for (int off = 32; off >= 1; off >>= 1) {
      p0 += __shfl_xor(p0, off, 64);
      p1 += __shfl_xor(p1, off, 64);
      p2 += __shfl_xor(p2, off, 64);
      p3 += __shfl_xor(p3, off, 64);
    }
    upd(p0, xs0);
    upd(p1, xs1);
    upd(p2, xs2);
    upd(p3, xs3);
  }
  for (; j < r1; ++j) {
    const int2 q = es[j];
    const float4 xs = *(const float4*)(xl + (size_t)q.y * HID + c0);
    float e0, e1, e2, e3;
    eecalc(eattr + (size_t)q.x * DE, e0, e1, e2, e3);
    s0 += e0; s1 += e1; s2 += e2; s3 += e3;
    float p = pfin(xs, e0, e1, e2, e3);
#pragma unroll
    for (int off = 32; off >= 1; off >>= 1) p += __shfl_xor(p, off, 64);
    upd(p, xs);
  }

  // self loop: ee_self = (sum of ee)/deg
  {
    const float invd = 1.f / (float)(deg > 0 ? deg : 1);
    const float4 xs = *(const float4*)(xl + (size_t)node * HID + c0);
    float p = pfin(xs, s0 * invd, s1 * invd, s2 * invd, s3 * invd);
#pragma unroll
    for (int off = 32; off >= 1; off >>= 1) p += __shfl_xor(p, off, 64);
    upd(p, xs);
  }

  const float inv = 1.f / (ssum + 1e-16f);
  const float4 bv = *(const float4*)(bias + c0);
  float4 o;
  o.x = fmaf(a0, inv, bv.x);
  o.y = fmaf(a1, inv, bv.y);
  o.z = fmaf(a2, inv, bv.z);
  o.w = fmaf(a3, inv, bv.w);
  *(float4*)(hout + (size_t)node * HID + c0) = o;
}

// ---------------- layer-2 node transforms ----------------

__global__ __launch_bounds__(256) void k_xform2(const float* __restrict__ h,
                                                const float* __restrict__ Wl,
                                                const float* __restrict__ bl,
                                                const float* __restrict__ Wr,
                                                const float* __restrict__ br,
                                                float* __restrict__ xl2,
                                                float* __restrict__ xr2) {
  const int t = threadIdx.x;
  const int c = t & 63;
  const int wv = t >> 6;
  const int cc = c & 31;
  const int r0 = blockIdx.x * 32 + wv * 8;
  const float* __restrict__ Wp = (c < 32) ? Wl : Wr;
  const float* __restrict__ bp = (c < 32) ? bl : br;
  float* __restrict__ op = (c < 32) ? xl2 : xr2;

  int rr[8];
#pragma unroll
  for (int i = 0; i < 8; ++i) {
    int r = r0 + i;
    rr[i] = r < NN ? r : NN - 1;
  }
  float acc[8];
#pragma unroll
  for (int i = 0; i < 8; ++i) acc[i] = 0.f;
#pragma unroll 4
  for (int k = 0; k < HID; ++k) {
    const float wval = Wp[k * OUTD + cc];
#pragma unroll
    for (int i = 0; i < 8; ++i) {
      acc[i] = fmaf(h[(size_t)rr[i] * HID + k], wval, acc[i]);
    }
  }
  const float bb = bp[cc];
#pragma unroll
  for (int i = 0; i < 8; ++i) {
    int r = r0 + i;
    if (r < NN) op[(size_t)r * OUTD + cc] = acc[i] + bb;
  }
}

// ---------------- layer-2 fused edge kernel ----------------
// wave/node; two independent half-wave softmax states, unroll-4 per half
// (8 edges in flight per wave); self-loop from accumulated ee sums.

__global__ __launch_bounds__(256) void k_edge2(
    const float* __restrict__ xl2, const float* __restrict__ xr2,
    const float* __restrict__ eattr, const int* __restrict__ rowptr,
    const int2* __restrict__ es, const float* __restrict__ We2,
    const float* __restrict__ att2, float* __restrict__ partials) {
  __shared__ float sacc[OUTD];
  const int tid = threadIdx.x;
  const int lane = tid & 63;
  const int wid = tid >> 6;
  const int node = blockIdx.x * 4 + wid;
  const int c = lane & 31;
  const int half = lane >> 5;

  if (tid < OUTD) sacc[tid] = 0.f;
  __syncthreads();

  float we2[DE];
#pragma unroll
  for (int k = 0; k < DE; ++k) we2[k] = We2[k * OUTD + c];
  const float attc = att2[c];
  const float xrc = xr2[(size_t)node * OUTD + c];
  const int r0 = rowptr[node], r1 = rowptr[node + 1];
  const int deg = r1 - r0;

  float m = -3.0e38f, ssum = 0.f, acc = 0.f, see = 0.f;

  auto eecalc = [&](const float* __restrict__ ap) -> float {
    const float4* __restrict__ eb = (const float4*)ap;
    const float4 A0 = eb[0], A1 = eb[1], A2 = eb[2], A3 = eb[3];
    float ee = A0.x * we2[0];
    ee = fmaf(A0.y, we2[1], ee);
    ee = fmaf(A0.z, we2[2], ee);
    ee = fmaf(A0.w, we2[3], ee);
    ee = fmaf(A1.x, we2[4], ee);
    ee = fmaf(A1.y, we2[5], ee);
    ee = fmaf(A1.z, we2[6], ee);
    ee = fmaf(A1.w, we2[7], ee);
    ee = fmaf(A2.x, we2[8], ee);
    ee = fmaf(A2.y, we2[9], ee);
    ee = fmaf(A2.z, we2[10], ee);
    ee = fmaf(A2.w, we2[11], ee);
    ee = fmaf(A3.x, we2[12], ee);
    ee = fmaf(A3.y, we2[13], ee);
    ee = fmaf(A3.z, we2[14], ee);
    ee = fmaf(A3.w, we2[15], ee);
    return ee;
  };
  auto pfin = [&](float xs, float ee) -> float {
    float z = xs + xrc + ee;
    z = fmaxf(z, SLOPE * z);
    return z * attc;
  };
  auto upd = [&](float p, float xs) {
    const float mn = fmaxf(m, p);
    const float sc = __expf(m - mn);
    const float w = __expf(p - mn);
    ssum = fmaf(ssum, sc, w);
    acc = fmaf(acc, sc, w * xs);
    m = mn;
  };

  int j = r0 + half;
  for (; j + 6 < r1; j += 8) {
    const int2 q0 = es[j], q1 = es[j + 2], q2 = es[j + 4], q3 = es[j + 6];
    const float xs0 = xl2[(size_t)q0.y * OUTD + c];
    const float xs1 = xl2[(size_t)q1.y * OUTD + c];
    const float xs2 = xl2[(size_t)q2.y * OUTD + c];
    const float xs3 = xl2[(size_t)q3.y * OUTD + c];
    const float ee0 = eecalc(eattr + (size_t)q0.x * DE);
    const float ee1 = eecalc(eattr + (size_t)q1.x * DE);
    const float ee2 = eecalc(eattr + (size_t)q2.x * DE);
    const float ee3 = eecalc(eattr + (size_t)q3.x * DE);
    see += (ee0 + ee1) + (ee2 + ee3);
    float p0 = pfin(xs0, ee0);
    float p1 = pfin(xs1, ee1);
    float p2 = pfin(xs2, ee2);
    float p3 = pfin(xs3, ee3);
#pragma unroll
    for (int off = 16; off >= 1; off >>= 1) {
      p0 += __shfl_xor(p0, off, 64);
      p1 += __shfl_xor(p1, off, 64);
      p2 += __shfl_xor(p2, off, 64);
      p3 += __shfl_xor(p3, off, 64);
    }
    upd(p0, xs0);
    upd(p1, xs1);
    upd(p2, xs2);
    upd(p3, xs3);
  }
  for (; j < r1; j += 2) {
    const int2 q = es[j];
    const float xs = xl2[(size_t)q.y * OUTD + c];
    const float ee = eecalc(eattr + (size_t)q.x * DE);
    see += ee;
    float p = pfin(xs, ee);
#pragma unroll
    for (int off = 16; off >= 1; off >>= 1) p += __shfl_xor(p, off, 64);
    upd(p, xs);
  }

  // merge ee sums across halves, then half 0 processes the self loop
  see += __shfl_xor(see, 32, 64);
  if (half == 0) {
    const float invd = 1.f / (float)(deg > 0 ? deg : 1);
    const float xs = xl2[(size_t)node * OUTD + c];
    float p = pfin(xs, see * invd);
#pragma unroll
    for (int off = 16; off >= 1; off >>= 1) p += __shfl_xor(p, off, 64);
    upd(p, xs);
  }

  // merge the two half-wave states (associative online-softmax merge)
  const float mo = __shfl_xor(m, 32, 64);
  const float so = __shfl_xor(ssum, 32, 64);
  const float ao = __shfl_xor(acc, 32, 64);
  const float mn = fmaxf(m, mo);
  const float sc0 = __expf(m - mn);
  const float sc1 = __expf(mo - mn);
  const float S = ssum * sc0 + so * sc1;
  const float A = acc * sc0 + ao * sc1;
  const float h2 = A / (S + 1e-16f);

  if (lane < OUTD) atomicAdd(&sacc[c], h2);
  __syncthreads();
  if (tid < OUTD) partials[(size_t)blockIdx.x * OUTD + tid] = sacc[tid];
}

// ---------------- final mean over nodes + bias2 ----------------

__global__ __launch_bounds__(256) void k_final(const float* __restrict__ partials,
                                               const float* __restrict__ bias2,
                                               float* __restrict__ out, int nblk) {
  __shared__ float lds[256];
  const int cch = blockIdx.x;  // 0..31
  const int t = threadIdx.x;
  float s = 0.f;
  for (int b = t; b < nblk; b += 256) s += partials[(size_t)b * OUTD + cch];
  lds[t] = s;
  __syncthreads();
  for (int off = 128; off >= 1; off >>= 1) {
    if (t < off) lds[t] += lds[t + off];
    __syncthreads();
  }
  if (t == 0) out[cch] = lds[0] * (1.f / (float)NN) + bias2[cch];
}

// ---------------- host ----------------

static inline size_t alup(size_t x) { return (x + 255) & ~(size_t)255; }

extern "C" void kernel_launch(void* const* d_in, const int* in_sizes, int n_in,
                              void* d_out, int out_size, void* d_ws, size_t ws_size,
                              hipStream_t stream) {
  (void)in_sizes; (void)n_in; (void)out_size; (void)ws_size;
  const float* x = (const float*)d_in[0];
  const int* ei = (const int*)d_in[1];
  const float* ea = (const float*)d_in[2];
  const float* Wl1 = (const float*)d_in[3];
  const float* bl1 = (const float*)d_in[4];
  const float* Wr1 = (const float*)d_in[5];
  const float* br1 = (const float*)d_in[6];
  const float* We1 = (const float*)d_in[7];
  const float* att1 = (const float*)d_in[8];
  const float* bias1 = (const float*)d_in[9];
  const float* Wl2 = (const float*)d_in[10];
  const float* bl2 = (const float*)d_in[11];
  const float* Wr2 = (const float*)d_in[12];
  const float* br2 = (const float*)d_in[13];
  const float* We2 = (const float*)d_in[14];
  const float* att2 = (const float*)d_in[15];
  const float* bias2 = (const float*)d_in[16];
  const int* srcv = ei;
  const int* dstv = ei + NE;

  char* w = (char*)d_ws;
  int* deg = (int*)w;        w += alup((size_t)NN * 4);
  int* fill = (int*)w;       w += alup((size_t)NN * 4);
  int* rowptr = (int*)w;     w += alup((size_t)(NN + 1) * 4);
  int2* es = (int2*)w;       w += alup((size_t)NE * 8);
  float* xl1 = (float*)w;    w += alup((size_t)NN * HID * 4);
  float* xr1 = (float*)w;    w += alup((size_t)NN * HID * 4);
  float* h = (float*)w;      w += alup((size_t)NN * HID * 4);
  float* partials = (float*)w;  // 12500*32 floats
  float* xl2 = xl1;
  float* xr2 = xr1;

  float* out = (float*)d_out;
  const int nblkNode4 = NN / 4;  // 12500

  hipMemsetAsync(deg, 0, (size_t)NN * 4, stream);
  hipMemsetAsync(fill, 0, (size_t)NN * 4, stream);

  k_count<<<FILLBLKS, 256, 0, stream>>>(dstv, deg);
  k_scan<<<1, 1024, 0, stream>>>(deg, rowptr);
  k_fill_xform1<<<FILLBLKS + NN / 16, 256, 0, stream>>>(
      srcv, dstv, rowptr, fill, es, x, Wl1, bl1, Wr1, br1, xl1, xr1);
  k_edge1<<<nblkNode4, 256, 0, stream>>>(xl1, xr1, ea, rowptr, es, We1, att1,
                                         bias1, h);
  k_xform2<<<(NN + 31) / 32, 256, 0, stream>>>(h, Wl2, bl2, Wr2, br2, xl2, xr2);
  k_edge2<<<nblkNode4, 256, 0, stream>>>(xl2, xr2, ea, rowptr, es, We2, att2,
                                         partials);
  k_final<<<OUTD, 256, 0, stream>>>(partials, bias2, out, nblkNode4);
}

// Round 4
// 720.860 us; speedup vs baseline: 1.1341x; 1.1341x over previous
//
#include <hip/hip_runtime.h>
#include <hip/hip_bf16.h>
#include <stdint.h>

// GATv2 x2 fused pipeline, fp32 end-to-end.
// N=50000 nodes, E=800000 edges, 128 -> 256 -> 32, mean over nodes -> [32].

#define NN 50000
#define NE 800000
#define DIN 128
#define DE 16
#define HID 256
#define OUTD 32
#define SLOPE 0.2f
#define FILLBLKS 3125

__device__ __forceinline__ float rfl(float x) {
  return __int_as_float(__builtin_amdgcn_readfirstlane(__float_as_int(x)));
}

// ---------------- CSR build ----------------

__global__ void k_count(const int* __restrict__ dstv, int* __restrict__ deg) {
  int e = blockIdx.x * 256 + threadIdx.x;
  if (e < NE) atomicAdd(&deg[dstv[e]], 1);
}

__global__ __launch_bounds__(1024) void k_scan(const int* __restrict__ deg,
                                               int* __restrict__ rowptr) {
  __shared__ int lds[1024];
  const int t = threadIdx.x;
  const int CH = 49;  // ceil(50000/1024)
  const int base = t * CH;
  int s = 0;
  for (int i = 0; i < CH; ++i) {
    int idx = base + i;
    if (idx < NN) s += deg[idx];
  }
  lds[t] = s;
  __syncthreads();
  int v = s;
  for (int off = 1; off < 1024; off <<= 1) {
    int add = (t >= off) ? lds[t - off] : 0;
    __syncthreads();
    v += add;
    lds[t] = v;
    __syncthreads();
  }
  int run = v - s;  // exclusive prefix
  for (int i = 0; i < CH; ++i) {
    int idx = base + i;
    if (idx < NN) {
      rowptr[idx] = run;
      run += deg[idx];
    }
  }
  if (t == 1023) rowptr[NN] = run;
}

// fill CSR with (edge_id, src) packed; overlapped with layer-1 node transforms
__global__ __launch_bounds__(256) void k_fill_xform1(
    const int* __restrict__ srcv, const int* __restrict__ dstv,
    const int* __restrict__ rowptr, int* __restrict__ fill, int2* __restrict__ es,
    const float* __restrict__ x, const float* __restrict__ Wl,
    const float* __restrict__ bl, const float* __restrict__ Wr,
    const float* __restrict__ br, float* __restrict__ xl, float* __restrict__ xr) {
  const int bid = blockIdx.x;
  if (bid < FILLBLKS) {
    int e = bid * 256 + threadIdx.x;
    if (e < NE) {
      int d = dstv[e];
      int p = atomicAdd(&fill[d], 1);
      es[rowptr[d] + p] = make_int2(e, srcv[e]);
    }
    return;
  }
  // ---- xform1: 16 rows x 256 cols per block ----
  const int c = threadIdx.x;
  const int r0 = (bid - FILLBLKS) * 16;
  float accl[16], accr[16];
#pragma unroll
  for (int r = 0; r < 16; ++r) { accl[r] = 0.f; accr[r] = 0.f; }
  const float* __restrict__ xb = x + (size_t)r0 * DIN;
#pragma unroll 4
  for (int k = 0; k < DIN; ++k) {
    const float wl = Wl[k * HID + c];
    const float wr = Wr[k * HID + c];
#pragma unroll
    for (int r = 0; r < 16; ++r) {
      const float xv = xb[r * DIN + k];
      accl[r] = fmaf(xv, wl, accl[r]);
      accr[r] = fmaf(xv, wr, accr[r]);
    }
  }
  const float blc = bl[c], brc = br[c];
#pragma unroll
  for (int r = 0; r < 16; ++r) {
    xl[(size_t)(r0 + r) * HID + c] = accl[r] + blc;
    xr[(size_t)(r0 + r) * HID + c] = accr[r] + brc;
  }
}

// ---------------- layer-1 fused edge kernel ----------------
// wave/node, online softmax (branch-free), unroll-4, ea values scalarized
// to SGPRs via readfirstlane; self-loop ee accumulated on the fly.

__global__ __launch_bounds__(256) void k_edge1(
    const float* __restrict__ xl, const float* __restrict__ xr,
    const float* __restrict__ eattr, const int* __restrict__ rowptr,
    const int2* __restrict__ es, const float* __restrict__ We,
    const float* __restrict__ att, const float* __restrict__ bias,
    float* __restrict__ hout) {
  const int tid = threadIdx.x;
  const int lane = tid & 63;
  const int wid = tid >> 6;
  const int node = blockIdx.x * 4 + wid;
  const int c0 = lane << 2;  // 4 channels per lane

  float we[DE][4];
#pragma unroll
  for (int k = 0; k < DE; ++k) {
    const float4 w4 = *(const float4*)(We + k * HID + c0);
    we[k][0] = w4.x; we[k][1] = w4.y; we[k][2] = w4.z; we[k][3] = w4.w;
  }
  const float4 attv = *(const float4*)(att + c0);
  const float4 xrv = *(const float4*)(xr + (size_t)node * HID + c0);
  const int r0 = rowptr[node], r1 = rowptr[node + 1];
  const int deg = r1 - r0;

  float m = -3.0e38f, ssum = 0.f;
  float a0 = 0.f, a1 = 0.f, a2 = 0.f, a3 = 0.f;
  float s0 = 0.f, s1 = 0.f, s2 = 0.f, s3 = 0.f;  // sum of ee over edges

  // ee for one edge; ea values scalarized (wave-uniform) -> SGPRs
  auto eecalc = [&](const float* __restrict__ ap, float& e0, float& e1, float& e2,
                    float& e3) {
    const float4* __restrict__ eb = (const float4*)ap;
    const float4 A0 = eb[0], A1 = eb[1], A2 = eb[2], A3 = eb[3];
    float a[16] = {rfl(A0.x), rfl(A0.y), rfl(A0.z), rfl(A0.w),
                   rfl(A1.x), rfl(A1.y), rfl(A1.z), rfl(A1.w),
                   rfl(A2.x), rfl(A2.y), rfl(A2.z), rfl(A2.w),
                   rfl(A3.x), rfl(A3.y), rfl(A3.z), rfl(A3.w)};
    e0 = e1 = e2 = e3 = 0.f;
#pragma unroll
    for (int k = 0; k < DE; ++k) {
      e0 = fmaf(a[k], we[k][0], e0);
      e1 = fmaf(a[k], we[k][1], e1);
      e2 = fmaf(a[k], we[k][2], e2);
      e3 = fmaf(a[k], we[k][3], e3);
    }
  };
  // leaky-relu (max form) + att dot, per-lane partial
  auto pfin = [&](const float4 xs, float e0, float e1, float e2, float e3) -> float {
    float z0 = xs.x + xrv.x + e0;
    float z1 = xs.y + xrv.y + e1;
    float z2 = xs.z + xrv.z + e2;
    float z3 = xs.w + xrv.w + e3;
    z0 = fmaxf(z0, SLOPE * z0);
    z1 = fmaxf(z1, SLOPE * z1);
    z2 = fmaxf(z2, SLOPE * z2);
    z3 = fmaxf(z3, SLOPE * z3);
    float p = z0 * attv.x;
    p = fmaf(z1, attv.y, p);
    p = fmaf(z2, attv.z, p);
    p = fmaf(z3, attv.w, p);
    return p;
  };
  // branch-free online-softmax update
  auto upd = [&](float p, const float4 xs) {
    const float mn = fmaxf(m, p);
    const float sc = __expf(m - mn);
    const float w = __expf(p - mn);
    ssum = fmaf(ssum, sc, w);
    a0 = fmaf(a0, sc, w * xs.x);
    a1 = fmaf(a1, sc, w * xs.y);
    a2 = fmaf(a2, sc, w * xs.z);
    a3 = fmaf(a3, sc, w * xs.w);
    m = mn;
  };

  int j = r0;
  for (; j + 4 <= r1; j += 4) {
    const int2 q0 = es[j], q1 = es[j + 1], q2 = es[j + 2], q3 = es[j + 3];
    const int s0i = __builtin_amdgcn_readfirstlane(q0.y);
    const int s1i = __builtin_amdgcn_readfirstlane(q1.y);
    const int s2i = __builtin_amdgcn_readfirstlane(q2.y);
    const int s3i = __builtin_amdgcn_readfirstlane(q3.y);
    const int e0i = __builtin_amdgcn_readfirstlane(q0.x);
    const int e1i = __builtin_amdgcn_readfirstlane(q1.x);
    const int e2i = __builtin_amdgcn_readfirstlane(q2.x);
    const int e3i = __builtin_amdgcn_readfirstlane(q3.x);
    const float4 xs0 = *(const float4*)(xl + (size_t)s0i * HID + c0);
    const float4 xs1 = *(const float4*)(xl + (size_t)s1i * HID + c0);
    const float4 xs2 = *(const float4*)(xl + (size_t)s2i * HID + c0);
    const float4 xs3 = *(const float4*)(xl + (size_t)s3i * HID + c0);
    float e00, e01, e02, e03, e10, e11, e12, e13;
    float e20, e21, e22, e23, e30, e31, e32, e33;
    eecalc(eattr + (size_t)e0i * DE, e00, e01, e02, e03);
    eecalc(eattr + (size_t)e1i * DE, e10, e11, e12, e13);
    eecalc(eattr + (size_t)e2i * DE, e20, e21, e22, e23);
    eecalc(eattr + (size_t)e3i * DE, e30, e31, e32, e33);
    s0 += (e00 + e10) + (e20 + e30);
    s1 += (e01 + e11) + (e21 + e31);
    s2 += (e02 + e12) + (e22 + e32);
    s3 += (e03 + e13) + (e23 + e33);
    float p0 = pfin(xs0, e00, e01, e02, e03);
    float p1 = pfin(xs1, e10, e11, e12, e13);
    float p2 = pfin(xs2, e20, e21, e22, e23);
    float p3 = pfin(xs3, e30, e31, e32, e33);
#pragma unroll
    for (int off = 32; off >= 1; off >>= 1) {
      p0 += __shfl_xor(p0, off, 64);
      p1 += __shfl_xor(p1, off, 64);
      p2 += __shfl_xor(p2, off, 64);
      p3 += __shfl_xor(p3, off, 64);
    }
    upd(p0, xs0);
    upd(p1, xs1);
    upd(p2, xs2);
    upd(p3, xs3);
  }
  for (; j < r1; ++j) {
    const int2 q = es[j];
    const int ei = __builtin_amdgcn_readfirstlane(q.x);
    const int si = __builtin_amdgcn_readfirstlane(q.y);
    const float4 xs = *(const float4*)(xl + (size_t)si * HID + c0);
    float e0, e1, e2, e3;
    eecalc(eattr + (size_t)ei * DE, e0, e1, e2, e3);
    s0 += e0; s1 += e1; s2 += e2; s3 += e3;
    float p = pfin(xs, e0, e1, e2, e3);
#pragma unroll
    for (int off = 32; off >= 1; off >>= 1) p += __shfl_xor(p, off, 64);
    upd(p, xs);
  }

  // self loop: ee_self = (sum of ee)/deg
  {
    const float invd = 1.f / (float)(deg > 0 ? deg : 1);
    const float4 xs = *(const float4*)(xl + (size_t)node * HID + c0);
    float p = pfin(xs, s0 * invd, s1 * invd, s2 * invd, s3 * invd);
#pragma unroll
    for (int off = 32; off >= 1; off >>= 1) p += __shfl_xor(p, off, 64);
    upd(p, xs);
  }

  const float inv = 1.f / (ssum + 1e-16f);
  const float4 bv = *(const float4*)(bias + c0);
  float4 o;
  o.x = fmaf(a0, inv, bv.x);
  o.y = fmaf(a1, inv, bv.y);
  o.z = fmaf(a2, inv, bv.z);
  o.w = fmaf(a3, inv, bv.w);
  *(float4*)(hout + (size_t)node * HID + c0) = o;
}

// ---------------- layer-2 node transforms ----------------

__global__ __launch_bounds__(256) void k_xform2(const float* __restrict__ h,
                                                const float* __restrict__ Wl,
                                                const float* __restrict__ bl,
                                                const float* __restrict__ Wr,
                                                const float* __restrict__ br,
                                                float* __restrict__ xl2,
                                                float* __restrict__ xr2) {
  const int t = threadIdx.x;
  const int c = t & 63;
  const int wv = t >> 6;
  const int cc = c & 31;
  const int r0 = blockIdx.x * 32 + wv * 8;
  const float* __restrict__ Wp = (c < 32) ? Wl : Wr;
  const float* __restrict__ bp = (c < 32) ? bl : br;
  float* __restrict__ op = (c < 32) ? xl2 : xr2;

  int rr[8];
#pragma unroll
  for (int i = 0; i < 8; ++i) {
    int r = r0 + i;
    rr[i] = r < NN ? r : NN - 1;
  }
  float acc[8];
#pragma unroll
  for (int i = 0; i < 8; ++i) acc[i] = 0.f;
#pragma unroll 4
  for (int k = 0; k < HID; ++k) {
    const float wval = Wp[k * OUTD + cc];
#pragma unroll
    for (int i = 0; i < 8; ++i) {
      acc[i] = fmaf(h[(size_t)rr[i] * HID + k], wval, acc[i]);
    }
  }
  const float bb = bp[cc];
#pragma unroll
  for (int i = 0; i < 8; ++i) {
    int r = r0 + i;
    if (r < NN) op[(size_t)r * OUTD + cc] = acc[i] + bb;
  }
}

// ---------------- layer-2 fused edge kernel ----------------
// wave/node; two independent half-wave softmax states, unroll-4 per half
// (8 edges in flight per wave); self-loop from accumulated ee sums.

__global__ __launch_bounds__(256) void k_edge2(
    const float* __restrict__ xl2, const float* __restrict__ xr2,
    const float* __restrict__ eattr, const int* __restrict__ rowptr,
    const int2* __restrict__ es, const float* __restrict__ We2,
    const float* __restrict__ att2, float* __restrict__ partials) {
  __shared__ float sacc[OUTD];
  const int tid = threadIdx.x;
  const int lane = tid & 63;
  const int wid = tid >> 6;
  const int node = blockIdx.x * 4 + wid;
  const int c = lane & 31;
  const int half = lane >> 5;

  if (tid < OUTD) sacc[tid] = 0.f;
  __syncthreads();

  float we2[DE];
#pragma unroll
  for (int k = 0; k < DE; ++k) we2[k] = We2[k * OUTD + c];
  const float attc = att2[c];
  const float xrc = xr2[(size_t)node * OUTD + c];
  const int r0 = rowptr[node], r1 = rowptr[node + 1];
  const int deg = r1 - r0;

  float m = -3.0e38f, ssum = 0.f, acc = 0.f, see = 0.f;

  auto eecalc = [&](const float* __restrict__ ap) -> float {
    const float4* __restrict__ eb = (const float4*)ap;
    const float4 A0 = eb[0], A1 = eb[1], A2 = eb[2], A3 = eb[3];
    float ee = A0.x * we2[0];
    ee = fmaf(A0.y, we2[1], ee);
    ee = fmaf(A0.z, we2[2], ee);
    ee = fmaf(A0.w, we2[3], ee);
    ee = fmaf(A1.x, we2[4], ee);
    ee = fmaf(A1.y, we2[5], ee);
    ee = fmaf(A1.z, we2[6], ee);
    ee = fmaf(A1.w, we2[7], ee);
    ee = fmaf(A2.x, we2[8], ee);
    ee = fmaf(A2.y, we2[9], ee);
    ee = fmaf(A2.z, we2[10], ee);
    ee = fmaf(A2.w, we2[11], ee);
    ee = fmaf(A3.x, we2[12], ee);
    ee = fmaf(A3.y, we2[13], ee);
    ee = fmaf(A3.z, we2[14], ee);
    ee = fmaf(A3.w, we2[15], ee);
    return ee;
  };
  auto pfin = [&](float xs, float ee) -> float {
    float z = xs + xrc + ee;
    z = fmaxf(z, SLOPE * z);
    return z * attc;
  };
  auto upd = [&](float p, float xs) {
    const float mn = fmaxf(m, p);
    const float sc = __expf(m - mn);
    const float w = __expf(p - mn);
    ssum = fmaf(ssum, sc, w);
    acc = fmaf(acc, sc, w * xs);
    m = mn;
  };

  int j = r0 + half;
  for (; j + 6 < r1; j += 8) {
    const int2 q0 = es[j], q1 = es[j + 2], q2 = es[j + 4], q3 = es[j + 6];
    const float xs0 = xl2[(size_t)q0.y * OUTD + c];
    const float xs1 = xl2[(size_t)q1.y * OUTD + c];
    const float xs2 = xl2[(size_t)q2.y * OUTD + c];
    const float xs3 = xl2[(size_t)q3.y * OUTD + c];
    const float ee0 = eecalc(eattr + (size_t)q0.x * DE);
    const float ee1 = eecalc(eattr + (size_t)q1.x * DE);
    const float ee2 = eecalc(eattr + (size_t)q2.x * DE);
    const float ee3 = eecalc(eattr + (size_t)q3.x * DE);
    see += (ee0 + ee1) + (ee2 + ee3);
    float p0 = pfin(xs0, ee0);
    float p1 = pfin(xs1, ee1);
    float p2 = pfin(xs2, ee2);
    float p3 = pfin(xs3, ee3);
#pragma unroll
    for (int off = 16; off >= 1; off >>= 1) {
      p0 += __shfl_xor(p0, off, 64);
      p1 += __shfl_xor(p1, off, 64);
      p2 += __shfl_xor(p2, off, 64);
      p3 += __shfl_xor(p3, off, 64);
    }
    upd(p0, xs0);
    upd(p1, xs1);
    upd(p2, xs2);
    upd(p3, xs3);
  }
  for (; j < r1; j += 2) {
    const int2 q = es[j];
    const float xs = xl2[(size_t)q.y * OUTD + c];
    const float ee = eecalc(eattr + (size_t)q.x * DE);
    see += ee;
    float p = pfin(xs, ee);
#pragma unroll
    for (int off = 16; off >= 1; off >>= 1) p += __shfl_xor(p, off, 64);
    upd(p, xs);
  }

  // merge ee sums across halves, then half 0 processes the self loop
  see += __shfl_xor(see, 32, 64);
  if (half == 0) {
    const float invd = 1.f / (float)(deg > 0 ? deg : 1);
    const float xs = xl2[(size_t)node * OUTD + c];
    float p = pfin(xs, see * invd);
#pragma unroll
    for (int off = 16; off >= 1; off >>= 1) p += __shfl_xor(p, off, 64);
    upd(p, xs);
  }

  // merge the two half-wave states (associative online-softmax merge)
  const float mo = __shfl_xor(m, 32, 64);
  const float so = __shfl_xor(ssum, 32, 64);
  const float ao = __shfl_xor(acc, 32, 64);
  const float mn = fmaxf(m, mo);
  const float sc0 = __expf(m - mn);
  const float sc1 = __expf(mo - mn);
  const float S = ssum * sc0 + so * sc1;
  const float A = acc * sc0 + ao * sc1;
  const float h2 = A / (S + 1e-16f);

  if (lane < OUTD) atomicAdd(&sacc[c], h2);
  __syncthreads();
  if (tid < OUTD) partials[(size_t)blockIdx.x * OUTD + tid] = sacc[tid];
}

// ---------------- final mean over nodes + bias2 ----------------

__global__ __launch_bounds__(256) void k_final(const float* __restrict__ partials,
                                               const float* __restrict__ bias2,
                                               float* __restrict__ out, int nblk) {
  __shared__ float lds[256];
  const int cch = blockIdx.x;  // 0..31
  const int t = threadIdx.x;
  float s = 0.f;
  for (int b = t; b < nblk; b += 256) s += partials[(size_t)b * OUTD + cch];
  lds[t] = s;
  __syncthreads();
  for (int off = 128; off >= 1; off >>= 1) {
    if (t < off) lds[t] += lds[t + off];
    __syncthreads();
  }
  if (t == 0) out[cch] = lds[0] * (1.f / (float)NN) + bias2[cch];
}

// ---------------- host ----------------

static inline size_t alup(size_t x) { return (x + 255) & ~(size_t)255; }

extern "C" void kernel_launch(void* const* d_in, const int* in_sizes, int n_in,
                              void* d_out, int out_size, void* d_ws, size_t ws_size,
                              hipStream_t stream) {
  (void)in_sizes; (void)n_in; (void)out_size; (void)ws_size;
  const float* x = (const float*)d_in[0];
  const int* ei = (const int*)d_in[1];
  const float* ea = (const float*)d_in[2];
  const float* Wl1 = (const float*)d_in[3];
  const float* bl1 = (const float*)d_in[4];
  const float* Wr1 = (const float*)d_in[5];
  const float* br1 = (const float*)d_in[6];
  const float* We1 = (const float*)d_in[7];
  const float* att1 = (const float*)d_in[8];
  const float* bias1 = (const float*)d_in[9];
  const float* Wl2 = (const float*)d_in[10];
  const float* bl2 = (const float*)d_in[11];
  const float* Wr2 = (const float*)d_in[12];
  const float* br2 = (const float*)d_in[13];
  const float* We2 = (const float*)d_in[14];
  const float* att2 = (const float*)d_in[15];
  const float* bias2 = (const float*)d_in[16];
  const int* srcv = ei;
  const int* dstv = ei + NE;

  char* w = (char*)d_ws;
  int* deg = (int*)w;        w += alup((size_t)NN * 4);
  int* fill = (int*)w;       w += alup((size_t)NN * 4);
  int* rowptr = (int*)w;     w += alup((size_t)(NN + 1) * 4);
  int2* es = (int2*)w;       w += alup((size_t)NE * 8);
  float* xl1 = (float*)w;    w += alup((size_t)NN * HID * 4);
  float* xr1 = (float*)w;    w += alup((size_t)NN * HID * 4);
  float* h = (float*)w;      w += alup((size_t)NN * HID * 4);
  float* partials = (float*)w;  // 12500*32 floats
  float* xl2 = xl1;
  float* xr2 = xr1;

  float* out = (float*)d_out;
  const int nblkNode4 = NN / 4;  // 12500

  hipMemsetAsync(deg, 0, (size_t)NN * 4, stream);
  hipMemsetAsync(fill, 0, (size_t)NN * 4, stream);

  k_count<<<FILLBLKS, 256, 0, stream>>>(dstv, deg);
  k_scan<<<1, 1024, 0, stream>>>(deg, rowptr);
  k_fill_xform1<<<FILLBLKS + NN / 16, 256, 0, stream>>>(
      srcv, dstv, rowptr, fill, es, x, Wl1, bl1, Wr1, br1, xl1, xr1);
  k_edge1<<<nblkNode4, 256, 0, stream>>>(xl1, xr1, ea, rowptr, es, We1, att1,
                                         bias1, h);
  k_xform2<<<(NN + 31) / 32, 256, 0, stream>>>(h, Wl2, bl2, Wr2, br2, xl2, xr2);
  k_edge2<<<nblkNode4, 256, 0, stream>>>(xl2, xr2, ea, rowptr, es, We2, att2,
                                         partials);
  k_final<<<OUTD, 256, 0, stream>>>(partials, bias2, out, nblkNode4);
}